// Round 2
// baseline (131.278 us; speedup 1.0000x reference)
//
#include <hip/hip_runtime.h>
#include <math.h>

// Problem constants (fixed by setup_inputs)
#define HH 736
#define WW 1280
#define NPIX (HH*WW)
#define NM 8        // markers
#define NBRD 4      // boards
#define MS 260      // marker fp/fa side (64*4 + 8 - 4)
#define BS 516      // board fa side (4*128 + 8 - 4)

// Workspace layout (float units)
#define OFF_MINV 0                       // 12*9 = 108 floats (scaled inverse homographies)
#define OFF_BBOX 108                     // 12*4 ints
#define OFF_SPOW 156                     // 4*3 floats (spec_power)
#define OFF_FAM  168                     // MS*MS floats (marker alpha table)
#define OFF_FAB  (OFF_FAM + MS*MS)       // BS*BS floats (board alpha table)
#define OFF_FP   (OFF_FAB + BS*BS)       // NM*MS*MS*3 floats, channel-interleaved
// total = OFF_FP + 8*260*260*3 = 1,956,424 floats ~= 7.83 MB of d_ws

struct K25 { float v[25]; };

// ---------------------------------------------------------------------------
// Setup: invert homographies (f64), scale by smtx, bboxes, spec_power.
// ---------------------------------------------------------------------------
__global__ void setup_kernel(const float* __restrict__ marker_h,
                             const float* __restrict__ board_h,
                             const float* __restrict__ refl,
                             const float* __restrict__ bview,
                             const float* __restrict__ bnorm,
                             const float* __restrict__ avg_color,
                             const float* __restrict__ bmax,
                             const float* __restrict__ rough,
                             const float* __restrict__ sscale,
                             float* __restrict__ minv_out,
                             int* __restrict__ bbox_out,
                             float* __restrict__ spow_out) {
  int t = threadIdx.x;
  if (t < 12) {
    const float* h = (t < NM) ? (marker_h + t*9) : (board_h + (t-NM)*9);
    // 3x3 inverse via adjugate in double
    double a=h[0],b=h[1],c=h[2],d=h[3],e=h[4],f=h[5],g=h[6],p=h[7],q=h[8];
    double A =  (e*q - f*p);
    double B = -(d*q - f*g);
    double C =  (d*p - e*g);
    double det = a*A + b*B + c*C;
    double id = 1.0/det;
    double inv[9];
    inv[0]= A*id;            inv[1]=-(b*q - c*p)*id;  inv[2]= (b*f - c*e)*id;
    inv[3]= B*id;            inv[4]= (a*q - c*g)*id;  inv[5]=-(a*f - c*d)*id;
    inv[6]= C*id;            inv[7]=-(a*p - b*g)*id;  inv[8]= (a*e - b*d)*id;
    // smtx = diag((S-4)/S, (S-4)/S, 1)
    float s0 = (t < NM) ? (float)(256.0/260.0) : (float)(512.0/516.0);
    minv_out[t*9+0]=(float)inv[0]*s0; minv_out[t*9+1]=(float)inv[1]*s0; minv_out[t*9+2]=(float)inv[2]*s0;
    minv_out[t*9+3]=(float)inv[3]*s0; minv_out[t*9+4]=(float)inv[4]*s0; minv_out[t*9+5]=(float)inv[5]*s0;
    minv_out[t*9+6]=(float)inv[6];    minv_out[t*9+7]=(float)inv[7];    minv_out[t*9+8]=(float)inv[8];
    // bbox from forward homography of corners (f32, like reference)
    const float cxs[4] = {-1.f, 1.f, 1.f, -1.f};
    const float cys[4] = {-1.f, -1.f, 1.f, 1.f};
    float mnx=1e30f, mny=1e30f, mxx=-1e30f, mxy=-1e30f;
    for (int k = 0; k < 4; ++k) {
      float X = h[0]*cxs[k] + h[1]*cys[k] + h[2];
      float Y = h[3]*cxs[k] + h[4]*cys[k] + h[5];
      float Z = h[6]*cxs[k] + h[7]*cys[k] + h[8];
      float sc = (fabsf(Z) > 1e-8f) ? 1.0f/(Z + 1e-8f) : 1.0f;
      float tx = X*sc, ty = Y*sc;
      mnx = fminf(mnx, tx); mny = fminf(mny, ty);
      mxx = fmaxf(mxx, tx); mxy = fmaxf(mxy, ty);
    }
    float lox = fminf(fmaxf(mnx - 2.0f, 0.f), (float)WW);
    float loy = fminf(fmaxf(mny - 2.0f, 0.f), (float)HH);
    float hix = fminf(fmaxf(mxx + 2.0f, 0.f), (float)WW);
    float hiy = fminf(fmaxf(mxy + 2.0f, 0.f), (float)HH);
    bbox_out[t*4+0] = (int)floorf(lox);
    bbox_out[t*4+1] = (int)floorf(loy);
    bbox_out[t*4+2] = (int)floorf(hix);
    bbox_out[t*4+3] = (int)floorf(hiy);
  }
  if (t >= 16 && t < 16 + NBRD) {
    int bidx = t - 16;
    float lx=refl[bidx*3+0], ly=refl[bidx*3+1], lz=refl[bidx*3+2];
    float vx=bview[bidx*3+0], vy=bview[bidx*3+1], vz=bview[bidx*3+2];
    float nx=bnorm[bidx*3+0], ny=bnorm[bidx*3+1], nz=bnorm[bidx*3+2];
    float r  = rough[bidx];
    float hx=(lx+vx)*0.5f, hy=(ly+vy)*0.5f, hz=(lz+vz)*0.5f;
    float hl=fmaxf(sqrtf(hx*hx+hy*hy+hz*hz), 1e-8f);
    hx/=hl; hy/=hl; hz/=hl;
    float NoH=fmaxf(0.f, nx*hx+ny*hy+nz*hz);
    float NoV=fmaxf(0.f, nx*vx+ny*vy+nz*vz);
    float NoL=fmaxf(0.f, nx*lx+ny*ly+nz*lz);
    float VoH=fmaxf(0.f, vx*hx+vy*hy+vz*hz);
    float al = r*r;
    float tmp = al / fmaxf(NoH*NoH*(al*al-1.f)+1.f, 1e-8f);
    float D = tmp*tmp*(float)(1.0/M_PI);
    float kk = al*0.5f;
    float G = NoL*NoV / fmaxf((NoL*(1.f-kk)+kk)*(NoV*(1.f-kk)+kk), 1e-8f);
    float co = VoH*(-5.55473f*VoH - 6.98316f);
    float F = 0.1f + 0.9f*exp2f(co);
    float f_s = D*G*F / fmaxf(4.f*NoL*NoV, 1e-8f);
    float smax = f_s*NoL*(float)M_PI;          // channel-identical -> max over c = itself
    float invs = 1.0f/(smax + 1e-8f);
    float fac = (1.1f - bmax[bidx]) * sscale[bidx];
    spow_out[bidx*3+0] = avg_color[bidx*3+0]*invs*fac;
    spow_out[bidx*3+1] = avg_color[bidx*3+1]*invs*fac;
    spow_out[bidx*3+2] = avg_color[bidx*3+2]*invs*fac;
  }
}

// ---------------------------------------------------------------------------
// Marker fp: repeat-4 upsample + edge pad 4 + 5x5 VALID conv, direct 25-tap.
// Output channel-interleaved: fp[((n*MS+y)*MS+x)*3 + c]
// ---------------------------------------------------------------------------
__global__ __launch_bounds__(256) void marker_blur_kernel(
    const float* __restrict__ markers, float* __restrict__ fp, K25 K) {
  int idx = blockIdx.x*256 + threadIdx.x;
  if (idx >= NM*MS*MS) return;
  int x = idx % MS; int t = idx / MS; int y = t % MS; int n = t / MS;
  const float* p = markers + n*3*4096;
  float a0=0.f, a1=0.f, a2=0.f;
  #pragma unroll
  for (int ky = 0; ky < 5; ++ky) {
    int iy = y + ky - 4; iy = min(max(iy, 0), 255);
    int py = iy >> 2;
    #pragma unroll
    for (int kx = 0; kx < 5; ++kx) {
      int ix = x + kx - 4; ix = min(max(ix, 0), 255);
      int px = ix >> 2;
      float w = K.v[ky*5+kx];
      int o = py*64 + px;
      a0 += w * p[o];
      a1 += w * p[4096 + o];
      a2 += w * p[8192 + o];
    }
  }
  int o = idx*3;
  fp[o+0]=a0; fp[o+1]=a1; fp[o+2]=a2;
}

// ---------------------------------------------------------------------------
// Alpha table: ones image zero-padded by 4, 5x5 VALID conv. ones at [4, S).
// ---------------------------------------------------------------------------
__global__ __launch_bounds__(256) void fa_kernel(float* __restrict__ out, int S, K25 K) {
  int idx = blockIdx.x*256 + threadIdx.x;
  if (idx >= S*S) return;
  int x = idx % S, y = idx / S;
  float a = 0.f;
  #pragma unroll
  for (int ky = 0; ky < 5; ++ky) {
    int iy = y + ky;
    bool oy = (iy >= 4) && (iy < S);
    #pragma unroll
    for (int kx = 0; kx < 5; ++kx) {
      int ix = x + kx;
      bool ox = (ix >= 4) && (ix < S);
      if (oy && ox) a += K.v[ky*5+kx];
    }
  }
  out[idx] = a;
}

// ---------------------------------------------------------------------------
// Main fused per-pixel kernel.
// ---------------------------------------------------------------------------
__global__ __launch_bounds__(256) void main_kernel(
    const float* __restrict__ image, const float* __restrict__ vd,
    const float* __restrict__ noise, const float* __restrict__ diffuse,
    const float* __restrict__ refl, const float* __restrict__ bn,
    const float* __restrict__ rough, const float* __restrict__ minv,
    const int* __restrict__ bbox, const float* __restrict__ spow,
    const float* __restrict__ fp, const float* __restrict__ faM,
    const float* __restrict__ faB, float* __restrict__ out) {
  __shared__ float s_minv[108];
  __shared__ int   s_bbox[48];
  __shared__ float s_spow[12], s_refl[12], s_bn[12], s_diff[12], s_rough[4];
  int tid = threadIdx.x;
  if (tid < 108) s_minv[tid] = minv[tid];
  if (tid < 48)  s_bbox[tid] = bbox[tid];
  if (tid < 12) {
    s_spow[tid] = spow[tid]; s_refl[tid] = refl[tid];
    s_bn[tid]   = bn[tid];   s_diff[tid] = diffuse[tid];
  }
  if (tid < 4) s_rough[tid] = rough[tid];
  __syncthreads();

  int idx = blockIdx.x*256 + tid;   // grid sized exactly H*W
  int x = idx % WW, y = idx / WW;
  float pxc = (float)x + 0.5f, pyc = (float)y + 0.5f;

  // ---- markers: pm (per channel), pma (channel-identical scalar) ----
  float pm0=0.f, pm1=0.f, pm2=0.f, pma=0.f;
  for (int n = 0; n < NM; ++n) {
    const int* bb = &s_bbox[n*4];
    if (x < bb[0] || x >= bb[2] || y < bb[1] || y >= bb[3]) continue;
    const float* m = &s_minv[n*9];
    float X = m[0]*pxc + m[1]*pyc + m[2];
    float Y = m[3]*pxc + m[4]*pyc + m[5];
    float Z = m[6]*pxc + m[7]*pyc + m[8];
    float sc = (fabsf(Z) > 1e-8f) ? 1.0f/(Z + 1e-8f) : 1.0f;
    float gx = (X*sc + 1.0f)*(0.5f*MS) - 0.5f;
    float gy = (Y*sc + 1.0f)*(0.5f*MS) - 0.5f;
    float x0f = floorf(gx), y0f = floorf(gy);
    float wx = gx - x0f, wy = gy - y0f;
    int x0 = (int)x0f, y0 = (int)y0f, x1 = x0+1, y1 = y0+1;
    bool okx0 = (x0 >= 0) & (x0 < MS), okx1 = (x1 >= 0) & (x1 < MS);
    bool oky0 = (y0 >= 0) & (y0 < MS), oky1 = (y1 >= 0) & (y1 < MS);
    int cx0 = min(max(x0,0),MS-1), cx1 = min(max(x1,0),MS-1);
    int cy0 = min(max(y0,0),MS-1), cy1 = min(max(y1,0),MS-1);
    float w00 = (okx0&&oky0) ? (1.f-wx)*(1.f-wy) : 0.f;
    float w10 = (okx1&&oky0) ? wx*(1.f-wy)       : 0.f;
    float w01 = (okx0&&oky1) ? (1.f-wx)*wy       : 0.f;
    float w11 = (okx1&&oky1) ? wx*wy             : 0.f;
    int i00 = cy0*MS+cx0, i10 = cy0*MS+cx1, i01 = cy1*MS+cx0, i11 = cy1*MS+cx1;
    const float* f0 = fp + (size_t)n*MS*MS*3;
    const float* t00 = f0 + i00*3; const float* t10 = f0 + i10*3;
    const float* t01 = f0 + i01*3; const float* t11 = f0 + i11*3;
    pm0 += t00[0]*w00 + t10[0]*w10 + t01[0]*w01 + t11[0]*w11;
    pm1 += t00[1]*w00 + t10[1]*w10 + t01[1]*w01 + t11[1]*w11;
    pm2 += t00[2]*w00 + t10[2]*w10 + t01[2]*w01 + t11[2]*w11;
    pma += faM[i00]*w00 + faM[i10]*w10 + faM[i01]*w01 + faM[i11]*w11;
  }

  // ---- boards: pb (diffuse*coverage), pba, hard-derived maps, spow ----
  float pb0=0.f, pb1=0.f, pb2=0.f, pba=0.f;
  float sd0=0.f, sd1=0.f, sd2=0.f;
  float sn0=0.f, sn1=0.f, sn2=0.f;
  float rg=0.f, sp0=0.f, sp1=0.f, sp2=0.f;
  for (int n = 0; n < NBRD; ++n) {
    int b = NM + n;
    const int* bb = &s_bbox[b*4];
    if (x < bb[0] || x >= bb[2] || y < bb[1] || y >= bb[3]) continue;
    const float* m = &s_minv[b*9];
    float X = m[0]*pxc + m[1]*pyc + m[2];
    float Y = m[3]*pxc + m[4]*pyc + m[5];
    float Z = m[6]*pxc + m[7]*pyc + m[8];
    float sc = (fabsf(Z) > 1e-8f) ? 1.0f/(Z + 1e-8f) : 1.0f;
    float gx = (X*sc + 1.0f)*(0.5f*BS) - 0.5f;
    float gy = (Y*sc + 1.0f)*(0.5f*BS) - 0.5f;
    float x0f = floorf(gx), y0f = floorf(gy);
    float wx = gx - x0f, wy = gy - y0f;
    int x0 = (int)x0f, y0 = (int)y0f, x1 = x0+1, y1 = y0+1;
    bool okx0 = (x0 >= 0) & (x0 < BS), okx1 = (x1 >= 0) & (x1 < BS);
    bool oky0 = (y0 >= 0) & (y0 < BS), oky1 = (y1 >= 0) & (y1 < BS);
    int cx0 = min(max(x0,0),BS-1), cx1 = min(max(x1,0),BS-1);
    int cy0 = min(max(y0,0),BS-1), cy1 = min(max(y1,0),BS-1);
    float w00 = (okx0&&oky0) ? (1.f-wx)*(1.f-wy) : 0.f;
    float w10 = (okx1&&oky0) ? wx*(1.f-wy)       : 0.f;
    float w01 = (okx0&&oky1) ? (1.f-wx)*wy       : 0.f;
    float w11 = (okx1&&oky1) ? wx*wy             : 0.f;
    int i00 = cy0*BS+cx0, i10 = cy0*BS+cx1, i01 = cy1*BS+cx0, i11 = cy1*BS+cx1;
    float cov = w00 + w10 + w01 + w11;           // board fp is constant diffuse
    float pa  = faB[i00]*w00 + faB[i10]*w10 + faB[i01]*w01 + faB[i11]*w11;
    pb0 += s_diff[n*3+0]*cov;
    pb1 += s_diff[n*3+1]*cov;
    pb2 += s_diff[n*3+2]*cov;
    pba += pa;
    float hd = (pa != 0.f) ? 1.f : 0.f;
    sd0 += hd*s_refl[n*3+0]; sd1 += hd*s_refl[n*3+1]; sd2 += hd*s_refl[n*3+2];
    sn0 += hd*s_bn[n*3+0];   sn1 += hd*s_bn[n*3+1];   sn2 += hd*s_bn[n*3+2];
    rg  += hd*s_rough[n];
    sp0 += pa*s_spow[n*3+0]; sp1 += pa*s_spow[n*3+1]; sp2 += pa*s_spow[n*3+2];
  }

  // ---- composite ----
  float i0 = image[idx], i1 = image[NPIX+idx], i2 = image[2*NPIX+idx];
  float st0 = pb0*(1.f-pma) + pb0*pm0*pma;
  float st1 = pb1*(1.f-pma) + pb1*pm1*pma;
  float st2 = pb2*(1.f-pma) + pb2*pm2*pma;
  float fin0 = i0*(1.f-pba) + i0*pba*st0;
  float fin1 = i1*(1.f-pba) + i1*pba*st1;
  float fin2 = i2*(1.f-pba) + i2*pba*st2;

  // ---- specular ----
  float nx = sn0 + noise[idx];
  float ny = sn1 + noise[NPIX+idx];
  float nz = sn2 + noise[2*NPIX+idx];
  float nl = fmaxf(sqrtf(nx*nx+ny*ny+nz*nz), 1e-8f);
  nx /= nl; ny /= nl; nz /= nl;
  float vx = vd[idx*3+0], vy = vd[idx*3+1], vz = vd[idx*3+2];
  float hx = (sd0+vx)*0.5f, hy = (sd1+vy)*0.5f, hz = (sd2+vz)*0.5f;
  float hl = fmaxf(sqrtf(hx*hx+hy*hy+hz*hz), 1e-8f);
  hx /= hl; hy /= hl; hz /= hl;
  float NoH = fmaxf(0.f, nx*hx+ny*hy+nz*hz);
  float NoV = fmaxf(0.f, nx*vx+ny*vy+nz*vz);
  float NoL = fmaxf(0.f, nx*sd0+ny*sd1+nz*sd2);
  float VoH = fmaxf(0.f, vx*hx+vy*hy+vz*hz);
  float al = rg*rg;
  float tmp = al / fmaxf(NoH*NoH*(al*al-1.f)+1.f, 1e-8f);
  float D = tmp*tmp*(float)(1.0/M_PI);
  float kk = al*0.5f;
  float G = NoL*NoV / fmaxf((NoL*(1.f-kk)+kk)*(NoV*(1.f-kk)+kk), 1e-8f);
  float co = VoH*(-5.55473f*VoH - 6.98316f);
  float F = 0.1f + 0.9f*exp2f(co);
  float f_s = D*G*F / fmaxf(4.f*NoL*NoV, 1e-8f);
  float spec = f_s*NoL*(float)M_PI;   // channel-identical (rough_map identical per c)

  out[idx]        = fin0 + spec*sp0;
  out[NPIX+idx]   = fin1 + spec*sp1;
  out[2*NPIX+idx] = fin2 + spec*sp2;
}

// ---------------------------------------------------------------------------
extern "C" void kernel_launch(void* const* d_in, const int* in_sizes, int n_in,
                              void* d_out, int out_size, void* d_ws, size_t ws_size,
                              hipStream_t stream) {
  const float* image    = (const float*)d_in[0];
  const float* vdirs    = (const float*)d_in[1];
  const float* markers  = (const float*)d_in[2];
  const float* marker_h = (const float*)d_in[3];
  const float* board_h  = (const float*)d_in[4];
  const float* refl     = (const float*)d_in[5];
  const float* bview    = (const float*)d_in[6];
  const float* bnorm    = (const float*)d_in[7];
  const float* avg_col  = (const float*)d_in[8];
  const float* bmax     = (const float*)d_in[9];
  const float* rough    = (const float*)d_in[10];
  const float* diffuse  = (const float*)d_in[11];
  const float* sscale   = (const float*)d_in[12];
  const float* noise    = (const float*)d_in[13];
  // d_in[14]=marker_scale(4), d_in[15]=board_scale(128): baked into MS/BS.

  float* ws   = (float*)d_ws;
  float* minv = ws + OFF_MINV;
  int*   bbox = (int*)(ws + OFF_BBOX);
  float* spow = ws + OFF_SPOW;
  float* faM  = ws + OFF_FAM;
  float* faB  = ws + OFF_FAB;
  float* fp   = ws + OFF_FP;
  float* outp = (float*)d_out;

  // disk kernel on host in f64 (bit-matches numpy) -> pass by value
  K25 K;
  {
    double w[25]; double s = 0.0;
    for (int dy = -2; dy <= 2; ++dy)
      for (int dx = -2; dx <= 2; ++dx) {
        double d = sqrt((double)(dx*dx + dy*dy));
        double v = 2.5 - d;
        v = v < 0.0 ? 0.0 : (v > 1.0 ? 1.0 : v);
        w[(dy+2)*5 + (dx+2)] = v; s += v;
      }
    for (int i = 0; i < 25; ++i) K.v[i] = (float)(w[i]/s);
  }

  hipLaunchKernelGGL(setup_kernel, dim3(1), dim3(64), 0, stream,
                     marker_h, board_h, refl, bview, bnorm, avg_col, bmax,
                     rough, sscale, minv, bbox, spow);
  hipLaunchKernelGGL(marker_blur_kernel, dim3((NM*MS*MS + 255)/256), dim3(256), 0, stream,
                     markers, fp, K);
  hipLaunchKernelGGL(fa_kernel, dim3((MS*MS + 255)/256), dim3(256), 0, stream, faM, MS, K);
  hipLaunchKernelGGL(fa_kernel, dim3((BS*BS + 255)/256), dim3(256), 0, stream, faB, BS, K);
  hipLaunchKernelGGL(main_kernel, dim3(NPIX/256), dim3(256), 0, stream,
                     image, vdirs, noise, diffuse, refl, bnorm, rough,
                     minv, bbox, spow, fp, faM, faB, outp);
}

// Round 8
// 127.389 us; speedup vs baseline: 1.0305x; 1.0305x over previous
//
#include <hip/hip_runtime.h>
#include <math.h>

// Problem constants (fixed by setup_inputs)
#define HH 736
#define WW 1280
#define NPIX (HH*WW)
#define NM 8        // markers
#define NBRD 4      // boards
#define MS 260      // marker fp/fa side (64*4 + 8 - 4)
#define BS 516      // board fa side (4*128 + 8 - 4)

// Workspace layout (float units)
#define OFF_MINV 0                       // 12*9 floats
#define OFF_BBOX 108                     // 12*4 ints
#define OFF_SPOW 156                     // 4*3 floats
#define OFF_FAM  168                     // MS*MS floats
#define OFF_FAB  (OFF_FAM + MS*MS)       // BS*BS floats
#define OFF_FP   (OFF_FAB + BS*BS)       // NM*MS*MS*3 floats (channel-interleaved)

// Fused precompute grid layout
#define BLUR_N (NM*MS*MS)                // 540800
#define BLUR_B ((BLUR_N + 255)/256)      // 2113
#define FAM_N  (MS*MS)                   // 67600
#define FAM_B  ((FAM_N + 255)/256)       // 265
#define FAB_N  (BS*BS)                   // 266256
#define FAB_B  ((FAB_N + 255)/256)       // 1041
#define PRE_B  (1 + BLUR_B + FAM_B + FAB_B)  // 3420

struct K25 { float v[25]; };

// ---------------------------------------------------------------------------
// Fused precompute: block 0 = setup (inverses/bboxes/spow); then marker blur,
// marker alpha table, board alpha table. All ranges independent.
// ---------------------------------------------------------------------------
__global__ __launch_bounds__(256) void precompute_kernel(
    const float* __restrict__ markers,
    const float* __restrict__ marker_h, const float* __restrict__ board_h,
    const float* __restrict__ refl, const float* __restrict__ bview,
    const float* __restrict__ bnorm, const float* __restrict__ avg_color,
    const float* __restrict__ bmax, const float* __restrict__ rough,
    const float* __restrict__ sscale,
    float* __restrict__ minv_out, int* __restrict__ bbox_out,
    float* __restrict__ spow_out, float* __restrict__ fp,
    float* __restrict__ faM, float* __restrict__ faB, K25 K) {
  int b = blockIdx.x;
  int tid = threadIdx.x;

  if (b == 0) {
    int t = tid;
    if (t < 12) {
      const float* h = (t < NM) ? (marker_h + t*9) : (board_h + (t-NM)*9);
      double a=h[0],bb=h[1],c=h[2],d=h[3],e=h[4],f=h[5],g=h[6],p=h[7],q=h[8];
      double A =  (e*q - f*p);
      double B = -(d*q - f*g);
      double C =  (d*p - e*g);
      double det = a*A + bb*B + c*C;
      double id = 1.0/det;
      double inv[9];
      inv[0]= A*id;             inv[1]=-(bb*q - c*p)*id;  inv[2]= (bb*f - c*e)*id;
      inv[3]= B*id;             inv[4]= (a*q - c*g)*id;   inv[5]=-(a*f - c*d)*id;
      inv[6]= C*id;             inv[7]=-(a*p - bb*g)*id;  inv[8]= (a*e - bb*d)*id;
      float s0 = (t < NM) ? (float)(256.0/260.0) : (float)(512.0/516.0);
      minv_out[t*9+0]=(float)inv[0]*s0; minv_out[t*9+1]=(float)inv[1]*s0; minv_out[t*9+2]=(float)inv[2]*s0;
      minv_out[t*9+3]=(float)inv[3]*s0; minv_out[t*9+4]=(float)inv[4]*s0; minv_out[t*9+5]=(float)inv[5]*s0;
      minv_out[t*9+6]=(float)inv[6];    minv_out[t*9+7]=(float)inv[7];    minv_out[t*9+8]=(float)inv[8];
      const float cxs[4] = {-1.f, 1.f, 1.f, -1.f};
      const float cys[4] = {-1.f, -1.f, 1.f, 1.f};
      float mnx=1e30f, mny=1e30f, mxx=-1e30f, mxy=-1e30f;
      for (int k = 0; k < 4; ++k) {
        float X = h[0]*cxs[k] + h[1]*cys[k] + h[2];
        float Y = h[3]*cxs[k] + h[4]*cys[k] + h[5];
        float Z = h[6]*cxs[k] + h[7]*cys[k] + h[8];
        float sc = (fabsf(Z) > 1e-8f) ? 1.0f/(Z + 1e-8f) : 1.0f;
        float tx = X*sc, ty = Y*sc;
        mnx = fminf(mnx, tx); mny = fminf(mny, ty);
        mxx = fmaxf(mxx, tx); mxy = fmaxf(mxy, ty);
      }
      float lox = fminf(fmaxf(mnx - 2.0f, 0.f), (float)WW);
      float loy = fminf(fmaxf(mny - 2.0f, 0.f), (float)HH);
      float hix = fminf(fmaxf(mxx + 2.0f, 0.f), (float)WW);
      float hiy = fminf(fmaxf(mxy + 2.0f, 0.f), (float)HH);
      bbox_out[t*4+0] = (int)floorf(lox);
      bbox_out[t*4+1] = (int)floorf(loy);
      bbox_out[t*4+2] = (int)floorf(hix);
      bbox_out[t*4+3] = (int)floorf(hiy);
    }
    if (t >= 16 && t < 16 + NBRD) {
      int bi = t - 16;
      float lx=refl[bi*3+0], ly=refl[bi*3+1], lz=refl[bi*3+2];
      float vx=bview[bi*3+0], vy=bview[bi*3+1], vz=bview[bi*3+2];
      float nx=bnorm[bi*3+0], ny=bnorm[bi*3+1], nz=bnorm[bi*3+2];
      float r  = rough[bi];
      float hx=(lx+vx)*0.5f, hy=(ly+vy)*0.5f, hz=(lz+vz)*0.5f;
      float hl=fmaxf(sqrtf(hx*hx+hy*hy+hz*hz), 1e-8f);
      hx/=hl; hy/=hl; hz/=hl;
      float NoH=fmaxf(0.f, nx*hx+ny*hy+nz*hz);
      float NoV=fmaxf(0.f, nx*vx+ny*vy+nz*vz);
      float NoL=fmaxf(0.f, nx*lx+ny*ly+nz*lz);
      float VoH=fmaxf(0.f, vx*hx+vy*hy+vz*hz);
      float al = r*r;
      float tmp = al / fmaxf(NoH*NoH*(al*al-1.f)+1.f, 1e-8f);
      float D = tmp*tmp*(float)(1.0/M_PI);
      float kk = al*0.5f;
      float G = NoL*NoV / fmaxf((NoL*(1.f-kk)+kk)*(NoV*(1.f-kk)+kk), 1e-8f);
      float co = VoH*(-5.55473f*VoH - 6.98316f);
      float F = 0.1f + 0.9f*exp2f(co);
      float f_s = D*G*F / fmaxf(4.f*NoL*NoV, 1e-8f);
      float smax = f_s*NoL*(float)M_PI;
      float invs = 1.0f/(smax + 1e-8f);
      float fac = (1.1f - bmax[bi]) * sscale[bi];
      spow_out[bi*3+0] = avg_color[bi*3+0]*invs*fac;
      spow_out[bi*3+1] = avg_color[bi*3+1]*invs*fac;
      spow_out[bi*3+2] = avg_color[bi*3+2]*invs*fac;
    }
    return;
  }

  if (b < 1 + BLUR_B) {
    int idx = (b-1)*256 + tid;
    if (idx >= BLUR_N) return;
    int x = idx % MS; int t = idx / MS; int y = t % MS; int n = t / MS;
    const float* p = markers + n*3*4096;
    float a0=0.f, a1=0.f, a2=0.f;
    #pragma unroll
    for (int ky = 0; ky < 5; ++ky) {
      int iy = y + ky - 4; iy = min(max(iy, 0), 255);
      int py = iy >> 2;
      #pragma unroll
      for (int kx = 0; kx < 5; ++kx) {
        int ix = x + kx - 4; ix = min(max(ix, 0), 255);
        int px = ix >> 2;
        float w = K.v[ky*5+kx];
        int o = py*64 + px;
        a0 += w * p[o];
        a1 += w * p[4096 + o];
        a2 += w * p[8192 + o];
      }
    }
    int o = idx*3;
    fp[o+0]=a0; fp[o+1]=a1; fp[o+2]=a2;
    return;
  }

  if (b < 1 + BLUR_B + FAM_B) {
    int idx = (b-1-BLUR_B)*256 + tid;
    if (idx >= FAM_N) return;
    int x = idx % MS, y = idx / MS;
    float a = 0.f;
    #pragma unroll
    for (int ky = 0; ky < 5; ++ky) {
      int iy = y + ky;
      bool oy = (iy >= 4) && (iy < MS);
      #pragma unroll
      for (int kx = 0; kx < 5; ++kx) {
        int ix = x + kx;
        bool ox = (ix >= 4) && (ix < MS);
        if (oy && ox) a += K.v[ky*5+kx];
      }
    }
    faM[idx] = a;
    return;
  }

  {
    int idx = (b-1-BLUR_B-FAM_B)*256 + tid;
    if (idx >= FAB_N) return;
    int x = idx % BS, y = idx / BS;
    float a = 0.f;
    #pragma unroll
    for (int ky = 0; ky < 5; ++ky) {
      int iy = y + ky;
      bool oy = (iy >= 4) && (iy < BS);
      #pragma unroll
      for (int kx = 0; kx < 5; ++kx) {
        int ix = x + kx;
        bool ox = (ix >= 4) && (ix < BS);
        if (oy && ox) a += K.v[ky*5+kx];
      }
    }
    faB[idx] = a;
    return;
  }
}

// ---------------------------------------------------------------------------
// Main fused per-pixel kernel — 4 pixels per thread, float4 I/O.
// ---------------------------------------------------------------------------
__global__ __launch_bounds__(256) void main_kernel(
    const float* __restrict__ image, const float* __restrict__ vd,
    const float* __restrict__ noise, const float* __restrict__ diffuse,
    const float* __restrict__ refl, const float* __restrict__ bn,
    const float* __restrict__ rough, const float* __restrict__ minv,
    const int* __restrict__ bbox, const float* __restrict__ spow,
    const float* __restrict__ fp, const float* __restrict__ faM,
    const float* __restrict__ faB, float* __restrict__ out) {
  __shared__ float s_minv[108];
  __shared__ int   s_bbox[48];
  __shared__ float s_spow[12], s_refl[12], s_bn[12], s_diff[12], s_rough[4];
  int tid = threadIdx.x;
  if (tid < 108) s_minv[tid] = minv[tid];
  if (tid < 48)  s_bbox[tid] = bbox[tid];
  if (tid < 12) {
    s_spow[tid] = spow[tid]; s_refl[tid] = refl[tid];
    s_bn[tid]   = bn[tid];   s_diff[tid] = diffuse[tid];
  }
  if (tid < 4) s_rough[tid] = rough[tid];
  __syncthreads();

  int base = (blockIdx.x*256 + tid)*4;   // WW%4==0 -> never wraps a row
  int x0i = base % WW;
  int y   = base / WW;
  float pyc = (float)y + 0.5f;

  // ---- markers ----
  float pm0[4]={0,0,0,0}, pm1[4]={0,0,0,0}, pm2[4]={0,0,0,0}, pma[4]={0,0,0,0};
  for (int n = 0; n < NM; ++n) {
    const int* bb = &s_bbox[n*4];
    if (y < bb[1] || y >= bb[3] || x0i+3 < bb[0] || x0i >= bb[2]) continue;
    const float* m = &s_minv[n*9];
    #pragma unroll
    for (int k = 0; k < 4; ++k) {
      int x = x0i + k;
      if (x < bb[0] || x >= bb[2]) continue;
      float pxc = (float)x + 0.5f;
      float X = m[0]*pxc + m[1]*pyc + m[2];
      float Y = m[3]*pxc + m[4]*pyc + m[5];
      float Z = m[6]*pxc + m[7]*pyc + m[8];
      float sc = (fabsf(Z) > 1e-8f) ? 1.0f/(Z + 1e-8f) : 1.0f;
      float gx = (X*sc + 1.0f)*(0.5f*MS) - 0.5f;
      float gy = (Y*sc + 1.0f)*(0.5f*MS) - 0.5f;
      float x0f = floorf(gx), y0f = floorf(gy);
      float wx = gx - x0f, wy = gy - y0f;
      int ix0 = (int)x0f, iy0 = (int)y0f, ix1 = ix0+1, iy1 = iy0+1;
      bool okx0 = (ix0 >= 0) & (ix0 < MS), okx1 = (ix1 >= 0) & (ix1 < MS);
      bool oky0 = (iy0 >= 0) & (iy0 < MS), oky1 = (iy1 >= 0) & (iy1 < MS);
      int cx0 = min(max(ix0,0),MS-1), cx1 = min(max(ix1,0),MS-1);
      int cy0 = min(max(iy0,0),MS-1), cy1 = min(max(iy1,0),MS-1);
      float w00 = (okx0&&oky0) ? (1.f-wx)*(1.f-wy) : 0.f;
      float w10 = (okx1&&oky0) ? wx*(1.f-wy)       : 0.f;
      float w01 = (okx0&&oky1) ? (1.f-wx)*wy       : 0.f;
      float w11 = (okx1&&oky1) ? wx*wy             : 0.f;
      int i00 = cy0*MS+cx0, i10 = cy0*MS+cx1, i01 = cy1*MS+cx0, i11 = cy1*MS+cx1;
      const float* f0 = fp + (size_t)n*MS*MS*3;
      const float* t00 = f0 + i00*3; const float* t10 = f0 + i10*3;
      const float* t01 = f0 + i01*3; const float* t11 = f0 + i11*3;
      pm0[k] += t00[0]*w00 + t10[0]*w10 + t01[0]*w01 + t11[0]*w11;
      pm1[k] += t00[1]*w00 + t10[1]*w10 + t01[1]*w01 + t11[1]*w11;
      pm2[k] += t00[2]*w00 + t10[2]*w10 + t01[2]*w01 + t11[2]*w11;
      pma[k] += faM[i00]*w00 + faM[i10]*w10 + faM[i01]*w01 + faM[i11]*w11;
    }
  }

  // ---- boards ----
  float pb0[4]={0,0,0,0}, pb1[4]={0,0,0,0}, pb2[4]={0,0,0,0}, pba[4]={0,0,0,0};
  float sd0[4]={0,0,0,0}, sd1[4]={0,0,0,0}, sd2[4]={0,0,0,0};
  float sn0[4]={0,0,0,0}, sn1[4]={0,0,0,0}, sn2[4]={0,0,0,0};
  float rg[4]={0,0,0,0},  sp0[4]={0,0,0,0}, sp1[4]={0,0,0,0}, sp2[4]={0,0,0,0};
  for (int n = 0; n < NBRD; ++n) {
    int bix = NM + n;
    const int* bb = &s_bbox[bix*4];
    if (y < bb[1] || y >= bb[3] || x0i+3 < bb[0] || x0i >= bb[2]) continue;
    const float* m = &s_minv[bix*9];
    #pragma unroll
    for (int k = 0; k < 4; ++k) {
      int x = x0i + k;
      if (x < bb[0] || x >= bb[2]) continue;
      float pxc = (float)x + 0.5f;
      float X = m[0]*pxc + m[1]*pyc + m[2];
      float Y = m[3]*pxc + m[4]*pyc + m[5];
      float Z = m[6]*pxc + m[7]*pyc + m[8];
      float sc = (fabsf(Z) > 1e-8f) ? 1.0f/(Z + 1e-8f) : 1.0f;
      float gx = (X*sc + 1.0f)*(0.5f*BS) - 0.5f;
      float gy = (Y*sc + 1.0f)*(0.5f*BS) - 0.5f;
      float x0f = floorf(gx), y0f = floorf(gy);
      float wx = gx - x0f, wy = gy - y0f;
      int ix0 = (int)x0f, iy0 = (int)y0f, ix1 = ix0+1, iy1 = iy0+1;
      bool okx0 = (ix0 >= 0) & (ix0 < BS), okx1 = (ix1 >= 0) & (ix1 < BS);
      bool oky0 = (iy0 >= 0) & (iy0 < BS), oky1 = (iy1 >= 0) & (iy1 < BS);
      int cx0 = min(max(ix0,0),BS-1), cx1 = min(max(ix1,0),BS-1);
      int cy0 = min(max(iy0,0),BS-1), cy1 = min(max(iy1,0),BS-1);
      float w00 = (okx0&&oky0) ? (1.f-wx)*(1.f-wy) : 0.f;
      float w10 = (okx1&&oky0) ? wx*(1.f-wy)       : 0.f;
      float w01 = (okx0&&oky1) ? (1.f-wx)*wy       : 0.f;
      float w11 = (okx1&&oky1) ? wx*wy             : 0.f;
      int i00 = cy0*BS+cx0, i10 = cy0*BS+cx1, i01 = cy1*BS+cx0, i11 = cy1*BS+cx1;
      float cov = w00 + w10 + w01 + w11;
      float pa  = faB[i00]*w00 + faB[i10]*w10 + faB[i01]*w01 + faB[i11]*w11;
      pb0[k] += s_diff[n*3+0]*cov;
      pb1[k] += s_diff[n*3+1]*cov;
      pb2[k] += s_diff[n*3+2]*cov;
      pba[k] += pa;
      float hd = (pa != 0.f) ? 1.f : 0.f;
      sd0[k] += hd*s_refl[n*3+0]; sd1[k] += hd*s_refl[n*3+1]; sd2[k] += hd*s_refl[n*3+2];
      sn0[k] += hd*s_bn[n*3+0];   sn1[k] += hd*s_bn[n*3+1];   sn2[k] += hd*s_bn[n*3+2];
      rg[k]  += hd*s_rough[n];
      sp0[k] += pa*s_spow[n*3+0]; sp1[k] += pa*s_spow[n*3+1]; sp2[k] += pa*s_spow[n*3+2];
    }
  }

  // ---- vectorized loads ----
  float i0a[4], i1a[4], i2a[4], n0a[4], n1a[4], n2a[4], vdl[12];
  *(float4*)i0a = *(const float4*)(image + base);
  *(float4*)i1a = *(const float4*)(image + NPIX + base);
  *(float4*)i2a = *(const float4*)(image + 2*NPIX + base);
  *(float4*)n0a = *(const float4*)(noise + base);
  *(float4*)n1a = *(const float4*)(noise + NPIX + base);
  *(float4*)n2a = *(const float4*)(noise + 2*NPIX + base);
  *(float4*)&vdl[0] = *(const float4*)(vd + (size_t)base*3);
  *(float4*)&vdl[4] = *(const float4*)(vd + (size_t)base*3 + 4);
  *(float4*)&vdl[8] = *(const float4*)(vd + (size_t)base*3 + 8);

  float o0a[4], o1a[4], o2a[4];
  #pragma unroll
  for (int k = 0; k < 4; ++k) {
    float st0 = pb0[k]*(1.f-pma[k]) + pb0[k]*pm0[k]*pma[k];
    float st1 = pb1[k]*(1.f-pma[k]) + pb1[k]*pm1[k]*pma[k];
    float st2 = pb2[k]*(1.f-pma[k]) + pb2[k]*pm2[k]*pma[k];
    float fin0 = i0a[k]*(1.f-pba[k]) + i0a[k]*pba[k]*st0;
    float fin1 = i1a[k]*(1.f-pba[k]) + i1a[k]*pba[k]*st1;
    float fin2 = i2a[k]*(1.f-pba[k]) + i2a[k]*pba[k]*st2;

    float nx = sn0[k] + n0a[k];
    float ny = sn1[k] + n1a[k];
    float nz = sn2[k] + n2a[k];
    float nl = fmaxf(sqrtf(nx*nx+ny*ny+nz*nz), 1e-8f);
    nx /= nl; ny /= nl; nz /= nl;
    float vx = vdl[3*k+0], vy = vdl[3*k+1], vz = vdl[3*k+2];
    float hx = (sd0[k]+vx)*0.5f, hy = (sd1[k]+vy)*0.5f, hz = (sd2[k]+vz)*0.5f;
    float hl = fmaxf(sqrtf(hx*hx+hy*hy+hz*hz), 1e-8f);
    hx /= hl; hy /= hl; hz /= hl;
    float NoH = fmaxf(0.f, nx*hx+ny*hy+nz*hz);
    float NoV = fmaxf(0.f, nx*vx+ny*vy+nz*vz);
    float NoL = fmaxf(0.f, nx*sd0[k]+ny*sd1[k]+nz*sd2[k]);
    float VoH = fmaxf(0.f, vx*hx+vy*hy+vz*hz);
    float al = rg[k]*rg[k];
    float tmp = al / fmaxf(NoH*NoH*(al*al-1.f)+1.f, 1e-8f);
    float D = tmp*tmp*(float)(1.0/M_PI);
    float kk = al*0.5f;
    float G = NoL*NoV / fmaxf((NoL*(1.f-kk)+kk)*(NoV*(1.f-kk)+kk), 1e-8f);
    float co = VoH*(-5.55473f*VoH - 6.98316f);
    float F = 0.1f + 0.9f*exp2f(co);
    float f_s = D*G*F / fmaxf(4.f*NoL*NoV, 1e-8f);
    float spec = f_s*NoL*(float)M_PI;

    o0a[k] = fin0 + spec*sp0[k];
    o1a[k] = fin1 + spec*sp1[k];
    o2a[k] = fin2 + spec*sp2[k];
  }
  *(float4*)(out + base)          = *(float4*)o0a;
  *(float4*)(out + NPIX + base)   = *(float4*)o1a;
  *(float4*)(out + 2*NPIX + base) = *(float4*)o2a;
}

// ---------------------------------------------------------------------------
extern "C" void kernel_launch(void* const* d_in, const int* in_sizes, int n_in,
                              void* d_out, int out_size, void* d_ws, size_t ws_size,
                              hipStream_t stream) {
  const float* image    = (const float*)d_in[0];
  const float* vdirs    = (const float*)d_in[1];
  const float* markers  = (const float*)d_in[2];
  const float* marker_h = (const float*)d_in[3];
  const float* board_h  = (const float*)d_in[4];
  const float* refl     = (const float*)d_in[5];
  const float* bview    = (const float*)d_in[6];
  const float* bnorm    = (const float*)d_in[7];
  const float* avg_col  = (const float*)d_in[8];
  const float* bmax     = (const float*)d_in[9];
  const float* rough    = (const float*)d_in[10];
  const float* diffuse  = (const float*)d_in[11];
  const float* sscale   = (const float*)d_in[12];
  const float* noise    = (const float*)d_in[13];

  float* ws   = (float*)d_ws;
  float* minv = ws + OFF_MINV;
  int*   bbox = (int*)(ws + OFF_BBOX);
  float* spow = ws + OFF_SPOW;
  float* faM  = ws + OFF_FAM;
  float* faB  = ws + OFF_FAB;
  float* fp   = ws + OFF_FP;
  float* outp = (float*)d_out;

  // disk kernel on host in f64 (bit-matches numpy) -> pass by value
  K25 K;
  {
    double w[25]; double s = 0.0;
    for (int dy = -2; dy <= 2; ++dy)
      for (int dx = -2; dx <= 2; ++dx) {
        double d = sqrt((double)(dx*dx + dy*dy));
        double v = 2.5 - d;
        v = v < 0.0 ? 0.0 : (v > 1.0 ? 1.0 : v);
        w[(dy+2)*5 + (dx+2)] = v; s += v;
      }
    for (int i = 0; i < 25; ++i) K.v[i] = (float)(w[i]/s);
  }

  hipLaunchKernelGGL(precompute_kernel, dim3(PRE_B), dim3(256), 0, stream,
                     markers, marker_h, board_h, refl, bview, bnorm, avg_col,
                     bmax, rough, sscale, minv, bbox, spow, fp, faM, faB, K);
  hipLaunchKernelGGL(main_kernel, dim3(NPIX/1024), dim3(256), 0, stream,
                     image, vdirs, noise, diffuse, refl, bnorm, rough,
                     minv, bbox, spow, fp, faM, faB, outp);
}

// Round 9
// 123.260 us; speedup vs baseline: 1.0651x; 1.0335x over previous
//
#include <hip/hip_runtime.h>
#include <math.h>

// Problem constants (fixed by setup_inputs)
#define HH 736
#define WW 1280
#define NPIX (HH*WW)
#define NM 8        // markers
#define NBRD 4      // boards
#define MS 260      // marker fp/fa side (64*4 + 8 - 4)
#define BS 516      // board fa side (4*128 + 8 - 4)

// Workspace layout (float units)
#define OFF_MINV 0                       // 12*9 floats
#define OFF_BBOX 108                     // 12*4 ints
#define OFF_SPOW 156                     // 4*3 floats
#define OFF_FAM  168                     // MS*MS floats
#define OFF_FAB  (OFF_FAM + MS*MS)       // BS*BS floats
#define OFF_FP   (OFF_FAB + BS*BS)       // NM*MS*MS*3 floats (channel-interleaved)

// Fused precompute grid layout
#define BLUR_N (NM*MS*MS)                // 540800
#define BLUR_B ((BLUR_N + 255)/256)      // 2113
#define FAM_N  (MS*MS)                   // 67600
#define FAM_B  ((FAM_N + 255)/256)       // 265
#define FAB_N  (BS*BS)                   // 266256
#define FAB_B  ((FAB_N + 255)/256)       // 1041
#define PRE_B  (1 + BLUR_B + FAM_B + FAB_B)  // 3420

struct K25 { float v[25]; };

// ---------------------------------------------------------------------------
// Fused precompute: block 0 = setup (inverses/bboxes/spow); then marker blur,
// marker alpha table, board alpha table. All ranges independent.
// ---------------------------------------------------------------------------
__global__ __launch_bounds__(256) void precompute_kernel(
    const float* __restrict__ markers,
    const float* __restrict__ marker_h, const float* __restrict__ board_h,
    const float* __restrict__ refl, const float* __restrict__ bview,
    const float* __restrict__ bnorm, const float* __restrict__ avg_color,
    const float* __restrict__ bmax, const float* __restrict__ rough,
    const float* __restrict__ sscale,
    float* __restrict__ minv_out, int* __restrict__ bbox_out,
    float* __restrict__ spow_out, float* __restrict__ fp,
    float* __restrict__ faM, float* __restrict__ faB, K25 K) {
  int b = blockIdx.x;
  int tid = threadIdx.x;

  if (b == 0) {
    int t = tid;
    if (t < 12) {
      const float* h = (t < NM) ? (marker_h + t*9) : (board_h + (t-NM)*9);
      double a=h[0],bb=h[1],c=h[2],d=h[3],e=h[4],f=h[5],g=h[6],p=h[7],q=h[8];
      double A =  (e*q - f*p);
      double B = -(d*q - f*g);
      double C =  (d*p - e*g);
      double det = a*A + bb*B + c*C;
      double id = 1.0/det;
      double inv[9];
      inv[0]= A*id;             inv[1]=-(bb*q - c*p)*id;  inv[2]= (bb*f - c*e)*id;
      inv[3]= B*id;             inv[4]= (a*q - c*g)*id;   inv[5]=-(a*f - c*d)*id;
      inv[6]= C*id;             inv[7]=-(a*p - bb*g)*id;  inv[8]= (a*e - bb*d)*id;
      float s0 = (t < NM) ? (float)(256.0/260.0) : (float)(512.0/516.0);
      minv_out[t*9+0]=(float)inv[0]*s0; minv_out[t*9+1]=(float)inv[1]*s0; minv_out[t*9+2]=(float)inv[2]*s0;
      minv_out[t*9+3]=(float)inv[3]*s0; minv_out[t*9+4]=(float)inv[4]*s0; minv_out[t*9+5]=(float)inv[5]*s0;
      minv_out[t*9+6]=(float)inv[6];    minv_out[t*9+7]=(float)inv[7];    minv_out[t*9+8]=(float)inv[8];
      const float cxs[4] = {-1.f, 1.f, 1.f, -1.f};
      const float cys[4] = {-1.f, -1.f, 1.f, 1.f};
      float mnx=1e30f, mny=1e30f, mxx=-1e30f, mxy=-1e30f;
      for (int k = 0; k < 4; ++k) {
        float X = h[0]*cxs[k] + h[1]*cys[k] + h[2];
        float Y = h[3]*cxs[k] + h[4]*cys[k] + h[5];
        float Z = h[6]*cxs[k] + h[7]*cys[k] + h[8];
        float sc = (fabsf(Z) > 1e-8f) ? 1.0f/(Z + 1e-8f) : 1.0f;
        float tx = X*sc, ty = Y*sc;
        mnx = fminf(mnx, tx); mny = fminf(mny, ty);
        mxx = fmaxf(mxx, tx); mxy = fmaxf(mxy, ty);
      }
      float lox = fminf(fmaxf(mnx - 2.0f, 0.f), (float)WW);
      float loy = fminf(fmaxf(mny - 2.0f, 0.f), (float)HH);
      float hix = fminf(fmaxf(mxx + 2.0f, 0.f), (float)WW);
      float hiy = fminf(fmaxf(mxy + 2.0f, 0.f), (float)HH);
      bbox_out[t*4+0] = (int)floorf(lox);
      bbox_out[t*4+1] = (int)floorf(loy);
      bbox_out[t*4+2] = (int)floorf(hix);
      bbox_out[t*4+3] = (int)floorf(hiy);
    }
    if (t >= 16 && t < 16 + NBRD) {
      int bi = t - 16;
      float lx=refl[bi*3+0], ly=refl[bi*3+1], lz=refl[bi*3+2];
      float vx=bview[bi*3+0], vy=bview[bi*3+1], vz=bview[bi*3+2];
      float nx=bnorm[bi*3+0], ny=bnorm[bi*3+1], nz=bnorm[bi*3+2];
      float r  = rough[bi];
      float hx=(lx+vx)*0.5f, hy=(ly+vy)*0.5f, hz=(lz+vz)*0.5f;
      float hl=fmaxf(sqrtf(hx*hx+hy*hy+hz*hz), 1e-8f);
      hx/=hl; hy/=hl; hz/=hl;
      float NoH=fmaxf(0.f, nx*hx+ny*hy+nz*hz);
      float NoV=fmaxf(0.f, nx*vx+ny*vy+nz*vz);
      float NoL=fmaxf(0.f, nx*lx+ny*ly+nz*lz);
      float VoH=fmaxf(0.f, vx*hx+vy*hy+vz*hz);
      float al = r*r;
      float tmp = al / fmaxf(NoH*NoH*(al*al-1.f)+1.f, 1e-8f);
      float D = tmp*tmp*(float)(1.0/M_PI);
      float kk = al*0.5f;
      float G = NoL*NoV / fmaxf((NoL*(1.f-kk)+kk)*(NoV*(1.f-kk)+kk), 1e-8f);
      float co = VoH*(-5.55473f*VoH - 6.98316f);
      float F = 0.1f + 0.9f*exp2f(co);
      float f_s = D*G*F / fmaxf(4.f*NoL*NoV, 1e-8f);
      float smax = f_s*NoL*(float)M_PI;
      float invs = 1.0f/(smax + 1e-8f);
      float fac = (1.1f - bmax[bi]) * sscale[bi];
      spow_out[bi*3+0] = avg_color[bi*3+0]*invs*fac;
      spow_out[bi*3+1] = avg_color[bi*3+1]*invs*fac;
      spow_out[bi*3+2] = avg_color[bi*3+2]*invs*fac;
    }
    return;
  }

  if (b < 1 + BLUR_B) {
    // Marker blur: 5x5 window over 4x upsample touches <=2x2 source texels.
    // Bin the 25 weights into B00/B01/B10/B11 (VALU), then 4 gathers x 3 ch.
    int idx = (b-1)*256 + tid;
    if (idx >= BLUR_N) return;
    int x = idx % MS; int t = idx / MS; int y = t % MS; int n = t / MS;
    const float* p = markers + n*3*4096;
    int py0 = min(max(y-4, 0), 255) >> 2;
    int py1 = min(max(y,   0), 255) >> 2;
    int px0 = min(max(x-4, 0), 255) >> 2;
    int px1 = min(max(x,   0), 255) >> 2;
    float B00=0.f, B01=0.f, B10=0.f, B11=0.f;
    #pragma unroll
    for (int ky = 0; ky < 5; ++ky) {
      int py = min(max(y + ky - 4, 0), 255) >> 2;
      bool r1 = (py == py1) && (py1 != py0);
      #pragma unroll
      for (int kx = 0; kx < 5; ++kx) {
        int px = min(max(x + kx - 4, 0), 255) >> 2;
        bool c1 = (px == px1) && (px1 != px0);
        float w = K.v[ky*5+kx];
        if (r1) { if (c1) B11 += w; else B10 += w; }
        else    { if (c1) B01 += w; else B00 += w; }
      }
    }
    int o00 = py0*64+px0, o01 = py0*64+px1, o10 = py1*64+px0, o11 = py1*64+px1;
    float a0 = B00*p[o00]      + B01*p[o01]      + B10*p[o10]      + B11*p[o11];
    float a1 = B00*p[4096+o00] + B01*p[4096+o01] + B10*p[4096+o10] + B11*p[4096+o11];
    float a2 = B00*p[8192+o00] + B01*p[8192+o01] + B10*p[8192+o10] + B11*p[8192+o11];
    int o = idx*3;
    fp[o+0]=a0; fp[o+1]=a1; fp[o+2]=a2;
    return;
  }

  if (b < 1 + BLUR_B + FAM_B) {
    int idx = (b-1-BLUR_B)*256 + tid;
    if (idx >= FAM_N) return;
    int x = idx % MS, y = idx / MS;
    float a = 0.f;
    #pragma unroll
    for (int ky = 0; ky < 5; ++ky) {
      int iy = y + ky;
      bool oy = (iy >= 4) && (iy < MS);
      #pragma unroll
      for (int kx = 0; kx < 5; ++kx) {
        int ix = x + kx;
        bool ox = (ix >= 4) && (ix < MS);
        if (oy && ox) a += K.v[ky*5+kx];
      }
    }
    faM[idx] = a;
    return;
  }

  {
    int idx = (b-1-BLUR_B-FAM_B)*256 + tid;
    if (idx >= FAB_N) return;
    int x = idx % BS, y = idx / BS;
    float a = 0.f;
    #pragma unroll
    for (int ky = 0; ky < 5; ++ky) {
      int iy = y + ky;
      bool oy = (iy >= 4) && (iy < BS);
      #pragma unroll
      for (int kx = 0; kx < 5; ++kx) {
        int ix = x + kx;
        bool ox = (ix >= 4) && (ix < BS);
        if (oy && ox) a += K.v[ky*5+kx];
      }
    }
    faB[idx] = a;
    return;
  }
}

// ---------------------------------------------------------------------------
// Main fused per-pixel kernel — 4 pixels per thread, float4 I/O.
// Board-bbox early-out: outside all board bboxes, out == image exactly
// (pba=0 -> final=image; spow=0 & D=0 -> spec term +0). Markers only modulate
// the board color, so they're irrelevant there too.
// ---------------------------------------------------------------------------
__global__ __launch_bounds__(256) void main_kernel(
    const float* __restrict__ image, const float* __restrict__ vd,
    const float* __restrict__ noise, const float* __restrict__ diffuse,
    const float* __restrict__ refl, const float* __restrict__ bn,
    const float* __restrict__ rough, const float* __restrict__ minv,
    const int* __restrict__ bbox, const float* __restrict__ spow,
    const float* __restrict__ fp, const float* __restrict__ faM,
    const float* __restrict__ faB, float* __restrict__ out) {
  __shared__ float s_minv[108];
  __shared__ int   s_bbox[48];
  __shared__ float s_spow[12], s_refl[12], s_bn[12], s_diff[12], s_rough[4];
  int tid = threadIdx.x;
  if (tid < 108) s_minv[tid] = minv[tid];
  if (tid < 48)  s_bbox[tid] = bbox[tid];
  if (tid < 12) {
    s_spow[tid] = spow[tid]; s_refl[tid] = refl[tid];
    s_bn[tid]   = bn[tid];   s_diff[tid] = diffuse[tid];
  }
  if (tid < 4) s_rough[tid] = rough[tid];
  __syncthreads();

  int base = (blockIdx.x*256 + tid)*4;   // WW%4==0 -> never wraps a row
  int x0i = base % WW;
  int y   = base / WW;

  // ---- board-bbox early-out ----
  bool hasBoard = false;
  #pragma unroll
  for (int n = 0; n < NBRD; ++n) {
    const int* bb = &s_bbox[(NM+n)*4];
    hasBoard |= (y >= bb[1]) && (y < bb[3]) && (x0i+3 >= bb[0]) && (x0i < bb[2]);
  }
  if (!hasBoard) {
    *(float4*)(out + base)          = *(const float4*)(image + base);
    *(float4*)(out + NPIX + base)   = *(const float4*)(image + NPIX + base);
    *(float4*)(out + 2*NPIX + base) = *(const float4*)(image + 2*NPIX + base);
    return;
  }

  float pyc = (float)y + 0.5f;

  // ---- markers ----
  float pm0[4]={0,0,0,0}, pm1[4]={0,0,0,0}, pm2[4]={0,0,0,0}, pma[4]={0,0,0,0};
  for (int n = 0; n < NM; ++n) {
    const int* bb = &s_bbox[n*4];
    if (y < bb[1] || y >= bb[3] || x0i+3 < bb[0] || x0i >= bb[2]) continue;
    const float* m = &s_minv[n*9];
    #pragma unroll
    for (int k = 0; k < 4; ++k) {
      int x = x0i + k;
      if (x < bb[0] || x >= bb[2]) continue;
      float pxc = (float)x + 0.5f;
      float X = m[0]*pxc + m[1]*pyc + m[2];
      float Y = m[3]*pxc + m[4]*pyc + m[5];
      float Z = m[6]*pxc + m[7]*pyc + m[8];
      float sc = (fabsf(Z) > 1e-8f) ? 1.0f/(Z + 1e-8f) : 1.0f;
      float gx = (X*sc + 1.0f)*(0.5f*MS) - 0.5f;
      float gy = (Y*sc + 1.0f)*(0.5f*MS) - 0.5f;
      float x0f = floorf(gx), y0f = floorf(gy);
      float wx = gx - x0f, wy = gy - y0f;
      int ix0 = (int)x0f, iy0 = (int)y0f, ix1 = ix0+1, iy1 = iy0+1;
      bool okx0 = (ix0 >= 0) & (ix0 < MS), okx1 = (ix1 >= 0) & (ix1 < MS);
      bool oky0 = (iy0 >= 0) & (iy0 < MS), oky1 = (iy1 >= 0) & (iy1 < MS);
      int cx0 = min(max(ix0,0),MS-1), cx1 = min(max(ix1,0),MS-1);
      int cy0 = min(max(iy0,0),MS-1), cy1 = min(max(iy1,0),MS-1);
      float w00 = (okx0&&oky0) ? (1.f-wx)*(1.f-wy) : 0.f;
      float w10 = (okx1&&oky0) ? wx*(1.f-wy)       : 0.f;
      float w01 = (okx0&&oky1) ? (1.f-wx)*wy       : 0.f;
      float w11 = (okx1&&oky1) ? wx*wy             : 0.f;
      int i00 = cy0*MS+cx0, i10 = cy0*MS+cx1, i01 = cy1*MS+cx0, i11 = cy1*MS+cx1;
      const float* f0 = fp + (size_t)n*MS*MS*3;
      const float* t00 = f0 + i00*3; const float* t10 = f0 + i10*3;
      const float* t01 = f0 + i01*3; const float* t11 = f0 + i11*3;
      pm0[k] += t00[0]*w00 + t10[0]*w10 + t01[0]*w01 + t11[0]*w11;
      pm1[k] += t00[1]*w00 + t10[1]*w10 + t01[1]*w01 + t11[1]*w11;
      pm2[k] += t00[2]*w00 + t10[2]*w10 + t01[2]*w01 + t11[2]*w11;
      pma[k] += faM[i00]*w00 + faM[i10]*w10 + faM[i01]*w01 + faM[i11]*w11;
    }
  }

  // ---- boards ----
  float pb0[4]={0,0,0,0}, pb1[4]={0,0,0,0}, pb2[4]={0,0,0,0}, pba[4]={0,0,0,0};
  float sd0[4]={0,0,0,0}, sd1[4]={0,0,0,0}, sd2[4]={0,0,0,0};
  float sn0[4]={0,0,0,0}, sn1[4]={0,0,0,0}, sn2[4]={0,0,0,0};
  float rg[4]={0,0,0,0},  sp0[4]={0,0,0,0}, sp1[4]={0,0,0,0}, sp2[4]={0,0,0,0};
  for (int n = 0; n < NBRD; ++n) {
    int bix = NM + n;
    const int* bb = &s_bbox[bix*4];
    if (y < bb[1] || y >= bb[3] || x0i+3 < bb[0] || x0i >= bb[2]) continue;
    const float* m = &s_minv[bix*9];
    #pragma unroll
    for (int k = 0; k < 4; ++k) {
      int x = x0i + k;
      if (x < bb[0] || x >= bb[2]) continue;
      float pxc = (float)x + 0.5f;
      float X = m[0]*pxc + m[1]*pyc + m[2];
      float Y = m[3]*pxc + m[4]*pyc + m[5];
      float Z = m[6]*pxc + m[7]*pyc + m[8];
      float sc = (fabsf(Z) > 1e-8f) ? 1.0f/(Z + 1e-8f) : 1.0f;
      float gx = (X*sc + 1.0f)*(0.5f*BS) - 0.5f;
      float gy = (Y*sc + 1.0f)*(0.5f*BS) - 0.5f;
      float x0f = floorf(gx), y0f = floorf(gy);
      float wx = gx - x0f, wy = gy - y0f;
      int ix0 = (int)x0f, iy0 = (int)y0f, ix1 = ix0+1, iy1 = iy0+1;
      bool okx0 = (ix0 >= 0) & (ix0 < BS), okx1 = (ix1 >= 0) & (ix1 < BS);
      bool oky0 = (iy0 >= 0) & (iy0 < BS), oky1 = (iy1 >= 0) & (iy1 < BS);
      int cx0 = min(max(ix0,0),BS-1), cx1 = min(max(ix1,0),BS-1);
      int cy0 = min(max(iy0,0),BS-1), cy1 = min(max(iy1,0),BS-1);
      float w00 = (okx0&&oky0) ? (1.f-wx)*(1.f-wy) : 0.f;
      float w10 = (okx1&&oky0) ? wx*(1.f-wy)       : 0.f;
      float w01 = (okx0&&oky1) ? (1.f-wx)*wy       : 0.f;
      float w11 = (okx1&&oky1) ? wx*wy             : 0.f;
      int i00 = cy0*BS+cx0, i10 = cy0*BS+cx1, i01 = cy1*BS+cx0, i11 = cy1*BS+cx1;
      float cov = w00 + w10 + w01 + w11;
      float pa  = faB[i00]*w00 + faB[i10]*w10 + faB[i01]*w01 + faB[i11]*w11;
      pb0[k] += s_diff[n*3+0]*cov;
      pb1[k] += s_diff[n*3+1]*cov;
      pb2[k] += s_diff[n*3+2]*cov;
      pba[k] += pa;
      float hd = (pa != 0.f) ? 1.f : 0.f;
      sd0[k] += hd*s_refl[n*3+0]; sd1[k] += hd*s_refl[n*3+1]; sd2[k] += hd*s_refl[n*3+2];
      sn0[k] += hd*s_bn[n*3+0];   sn1[k] += hd*s_bn[n*3+1];   sn2[k] += hd*s_bn[n*3+2];
      rg[k]  += hd*s_rough[n];
      sp0[k] += pa*s_spow[n*3+0]; sp1[k] += pa*s_spow[n*3+1]; sp2[k] += pa*s_spow[n*3+2];
    }
  }

  // ---- vectorized loads ----
  float i0a[4], i1a[4], i2a[4], n0a[4], n1a[4], n2a[4], vdl[12];
  *(float4*)i0a = *(const float4*)(image + base);
  *(float4*)i1a = *(const float4*)(image + NPIX + base);
  *(float4*)i2a = *(const float4*)(image + 2*NPIX + base);
  *(float4*)n0a = *(const float4*)(noise + base);
  *(float4*)n1a = *(const float4*)(noise + NPIX + base);
  *(float4*)n2a = *(const float4*)(noise + 2*NPIX + base);
  *(float4*)&vdl[0] = *(const float4*)(vd + (size_t)base*3);
  *(float4*)&vdl[4] = *(const float4*)(vd + (size_t)base*3 + 4);
  *(float4*)&vdl[8] = *(const float4*)(vd + (size_t)base*3 + 8);

  float o0a[4], o1a[4], o2a[4];
  #pragma unroll
  for (int k = 0; k < 4; ++k) {
    float st0 = pb0[k]*(1.f-pma[k]) + pb0[k]*pm0[k]*pma[k];
    float st1 = pb1[k]*(1.f-pma[k]) + pb1[k]*pm1[k]*pma[k];
    float st2 = pb2[k]*(1.f-pma[k]) + pb2[k]*pm2[k]*pma[k];
    float fin0 = i0a[k]*(1.f-pba[k]) + i0a[k]*pba[k]*st0;
    float fin1 = i1a[k]*(1.f-pba[k]) + i1a[k]*pba[k]*st1;
    float fin2 = i2a[k]*(1.f-pba[k]) + i2a[k]*pba[k]*st2;

    float nx = sn0[k] + n0a[k];
    float ny = sn1[k] + n1a[k];
    float nz = sn2[k] + n2a[k];
    float nl = fmaxf(sqrtf(nx*nx+ny*ny+nz*nz), 1e-8f);
    nx /= nl; ny /= nl; nz /= nl;
    float vx = vdl[3*k+0], vy = vdl[3*k+1], vz = vdl[3*k+2];
    float hx = (sd0[k]+vx)*0.5f, hy = (sd1[k]+vy)*0.5f, hz = (sd2[k]+vz)*0.5f;
    float hl = fmaxf(sqrtf(hx*hx+hy*hy+hz*hz), 1e-8f);
    hx /= hl; hy /= hl; hz /= hl;
    float NoH = fmaxf(0.f, nx*hx+ny*hy+nz*hz);
    float NoV = fmaxf(0.f, nx*vx+ny*vy+nz*vz);
    float NoL = fmaxf(0.f, nx*sd0[k]+ny*sd1[k]+nz*sd2[k]);
    float VoH = fmaxf(0.f, vx*hx+vy*hy+vz*hz);
    float al = rg[k]*rg[k];
    float tmp = al / fmaxf(NoH*NoH*(al*al-1.f)+1.f, 1e-8f);
    float D = tmp*tmp*(float)(1.0/M_PI);
    float kk = al*0.5f;
    float G = NoL*NoV / fmaxf((NoL*(1.f-kk)+kk)*(NoV*(1.f-kk)+kk), 1e-8f);
    float co = VoH*(-5.55473f*VoH - 6.98316f);
    float F = 0.1f + 0.9f*exp2f(co);
    float f_s = D*G*F / fmaxf(4.f*NoL*NoV, 1e-8f);
    float spec = f_s*NoL*(float)M_PI;

    o0a[k] = fin0 + spec*sp0[k];
    o1a[k] = fin1 + spec*sp1[k];
    o2a[k] = fin2 + spec*sp2[k];
  }
  *(float4*)(out + base)          = *(float4*)o0a;
  *(float4*)(out + NPIX + base)   = *(float4*)o1a;
  *(float4*)(out + 2*NPIX + base) = *(float4*)o2a;
}

// ---------------------------------------------------------------------------
extern "C" void kernel_launch(void* const* d_in, const int* in_sizes, int n_in,
                              void* d_out, int out_size, void* d_ws, size_t ws_size,
                              hipStream_t stream) {
  const float* image    = (const float*)d_in[0];
  const float* vdirs    = (const float*)d_in[1];
  const float* markers  = (const float*)d_in[2];
  const float* marker_h = (const float*)d_in[3];
  const float* board_h  = (const float*)d_in[4];
  const float* refl     = (const float*)d_in[5];
  const float* bview    = (const float*)d_in[6];
  const float* bnorm    = (const float*)d_in[7];
  const float* avg_col  = (const float*)d_in[8];
  const float* bmax     = (const float*)d_in[9];
  const float* rough    = (const float*)d_in[10];
  const float* diffuse  = (const float*)d_in[11];
  const float* sscale   = (const float*)d_in[12];
  const float* noise    = (const float*)d_in[13];

  float* ws   = (float*)d_ws;
  float* minv = ws + OFF_MINV;
  int*   bbox = (int*)(ws + OFF_BBOX);
  float* spow = ws + OFF_SPOW;
  float* faM  = ws + OFF_FAM;
  float* faB  = ws + OFF_FAB;
  float* fp   = ws + OFF_FP;
  float* outp = (float*)d_out;

  // disk kernel on host in f64 (bit-matches numpy) -> pass by value
  K25 K;
  {
    double w[25]; double s = 0.0;
    for (int dy = -2; dy <= 2; ++dy)
      for (int dx = -2; dx <= 2; ++dx) {
        double d = sqrt((double)(dx*dx + dy*dy));
        double v = 2.5 - d;
        v = v < 0.0 ? 0.0 : (v > 1.0 ? 1.0 : v);
        w[(dy+2)*5 + (dx+2)] = v; s += v;
      }
    for (int i = 0; i < 25; ++i) K.v[i] = (float)(w[i]/s);
  }

  hipLaunchKernelGGL(precompute_kernel, dim3(PRE_B), dim3(256), 0, stream,
                     markers, marker_h, board_h, refl, bview, bnorm, avg_col,
                     bmax, rough, sscale, minv, bbox, spow, fp, faM, faB, K);
  hipLaunchKernelGGL(main_kernel, dim3(NPIX/1024), dim3(256), 0, stream,
                     image, vdirs, noise, diffuse, refl, bnorm, rough,
                     minv, bbox, spow, fp, faM, faB, outp);
}

// Round 13
// 122.000 us; speedup vs baseline: 1.0761x; 1.0103x over previous
//
#include <hip/hip_runtime.h>
#include <math.h>

// Problem constants (fixed by setup_inputs)
#define HH 736
#define WW 1280
#define NPIX (HH*WW)
#define NM 8        // markers
#define NBRD 4      // boards
#define MS 260      // marker fp/fa side (64*4 + 8 - 4)
#define BS 516      // board fa side (4*128 + 8 - 4)

// Workspace layout (float units)
#define OFF_MINV 0                       // 12*9 floats
#define OFF_BBOX 108                     // 12*4 ints
#define OFF_SPOW 156                     // 4*3 floats
#define OFF_FAM  168                     // MS*MS floats
#define OFF_FAB  (OFF_FAM + MS*MS)       // BS*BS floats
#define OFF_FP   (OFF_FAB + BS*BS)       // NM*MS*MS*3 floats (channel-interleaved)

// Fused precompute grid layout
#define BLUR_N (NM*MS*MS)                // 540800
#define BLUR_B ((BLUR_N + 255)/256)      // 2113
#define FAM_N  (MS*MS)                   // 67600
#define FAM_B  ((FAM_N + 255)/256)       // 265
#define FAB_N  (BS*BS)                   // 266256
#define FAB_B  ((FAB_N + 255)/256)       // 1041
#define PRE_B  (1 + BLUR_B + FAM_B + FAB_B)  // 3420

struct K25 { float v[25]; };

// ---------------------------------------------------------------------------
// Fused precompute: block 0 = setup (inverses/bboxes/spow); then marker blur,
// marker alpha table, board alpha table. All ranges independent.
// ---------------------------------------------------------------------------
__global__ __launch_bounds__(256) void precompute_kernel(
    const float* __restrict__ markers,
    const float* __restrict__ marker_h, const float* __restrict__ board_h,
    const float* __restrict__ refl, const float* __restrict__ bview,
    const float* __restrict__ bnorm, const float* __restrict__ avg_color,
    const float* __restrict__ bmax, const float* __restrict__ rough,
    const float* __restrict__ sscale,
    float* __restrict__ minv_out, int* __restrict__ bbox_out,
    float* __restrict__ spow_out, float* __restrict__ fp,
    float* __restrict__ faM, float* __restrict__ faB, K25 K) {
  int b = blockIdx.x;
  int tid = threadIdx.x;

  if (b == 0) {
    int t = tid;
    if (t < 12) {
      const float* h = (t < NM) ? (marker_h + t*9) : (board_h + (t-NM)*9);
      double a=h[0],bb=h[1],c=h[2],d=h[3],e=h[4],f=h[5],g=h[6],p=h[7],q=h[8];
      double A =  (e*q - f*p);
      double B = -(d*q - f*g);
      double C =  (d*p - e*g);
      double det = a*A + bb*B + c*C;
      double id = 1.0/det;
      double inv[9];
      inv[0]= A*id;             inv[1]=-(bb*q - c*p)*id;  inv[2]= (bb*f - c*e)*id;
      inv[3]= B*id;             inv[4]= (a*q - c*g)*id;   inv[5]=-(a*f - c*d)*id;
      inv[6]= C*id;             inv[7]=-(a*p - bb*g)*id;  inv[8]= (a*e - bb*d)*id;
      float s0 = (t < NM) ? (float)(256.0/260.0) : (float)(512.0/516.0);
      minv_out[t*9+0]=(float)inv[0]*s0; minv_out[t*9+1]=(float)inv[1]*s0; minv_out[t*9+2]=(float)inv[2]*s0;
      minv_out[t*9+3]=(float)inv[3]*s0; minv_out[t*9+4]=(float)inv[4]*s0; minv_out[t*9+5]=(float)inv[5]*s0;
      minv_out[t*9+6]=(float)inv[6];    minv_out[t*9+7]=(float)inv[7];    minv_out[t*9+8]=(float)inv[8];
      const float cxs[4] = {-1.f, 1.f, 1.f, -1.f};
      const float cys[4] = {-1.f, -1.f, 1.f, 1.f};
      float mnx=1e30f, mny=1e30f, mxx=-1e30f, mxy=-1e30f;
      for (int k = 0; k < 4; ++k) {
        float X = h[0]*cxs[k] + h[1]*cys[k] + h[2];
        float Y = h[3]*cxs[k] + h[4]*cys[k] + h[5];
        float Z = h[6]*cxs[k] + h[7]*cys[k] + h[8];
        float sc = (fabsf(Z) > 1e-8f) ? 1.0f/(Z + 1e-8f) : 1.0f;
        float tx = X*sc, ty = Y*sc;
        mnx = fminf(mnx, tx); mny = fminf(mny, ty);
        mxx = fmaxf(mxx, tx); mxy = fmaxf(mxy, ty);
      }
      float lox = fminf(fmaxf(mnx - 2.0f, 0.f), (float)WW);
      float loy = fminf(fmaxf(mny - 2.0f, 0.f), (float)HH);
      float hix = fminf(fmaxf(mxx + 2.0f, 0.f), (float)WW);
      float hiy = fminf(fmaxf(mxy + 2.0f, 0.f), (float)HH);
      bbox_out[t*4+0] = (int)floorf(lox);
      bbox_out[t*4+1] = (int)floorf(loy);
      bbox_out[t*4+2] = (int)floorf(hix);
      bbox_out[t*4+3] = (int)floorf(hiy);
    }
    if (t >= 16 && t < 16 + NBRD) {
      int bi = t - 16;
      float lx=refl[bi*3+0], ly=refl[bi*3+1], lz=refl[bi*3+2];
      float vx=bview[bi*3+0], vy=bview[bi*3+1], vz=bview[bi*3+2];
      float nx=bnorm[bi*3+0], ny=bnorm[bi*3+1], nz=bnorm[bi*3+2];
      float r  = rough[bi];
      float hx=(lx+vx)*0.5f, hy=(ly+vy)*0.5f, hz=(lz+vz)*0.5f;
      float hl=fmaxf(sqrtf(hx*hx+hy*hy+hz*hz), 1e-8f);
      hx/=hl; hy/=hl; hz/=hl;
      float NoH=fmaxf(0.f, nx*hx+ny*hy+nz*hz);
      float NoV=fmaxf(0.f, nx*vx+ny*vy+nz*vz);
      float NoL=fmaxf(0.f, nx*lx+ny*ly+nz*lz);
      float VoH=fmaxf(0.f, vx*hx+vy*hy+vz*hz);
      float al = r*r;
      float tmp = al / fmaxf(NoH*NoH*(al*al-1.f)+1.f, 1e-8f);
      float D = tmp*tmp*(float)(1.0/M_PI);
      float kk = al*0.5f;
      float G = NoL*NoV / fmaxf((NoL*(1.f-kk)+kk)*(NoV*(1.f-kk)+kk), 1e-8f);
      float co = VoH*(-5.55473f*VoH - 6.98316f);
      float F = 0.1f + 0.9f*exp2f(co);
      float f_s = D*G*F / fmaxf(4.f*NoL*NoV, 1e-8f);
      float smax = f_s*NoL*(float)M_PI;
      float invs = 1.0f/(smax + 1e-8f);
      float fac = (1.1f - bmax[bi]) * sscale[bi];
      spow_out[bi*3+0] = avg_color[bi*3+0]*invs*fac;
      spow_out[bi*3+1] = avg_color[bi*3+1]*invs*fac;
      spow_out[bi*3+2] = avg_color[bi*3+2]*invs*fac;
    }
    return;
  }

  if (b < 1 + BLUR_B) {
    // Marker blur: 5x5 window over 4x upsample touches <=2x2 source texels.
    // Bin the 25 weights into B00/B01/B10/B11 (VALU), then 4 gathers x 3 ch.
    int idx = (b-1)*256 + tid;
    if (idx >= BLUR_N) return;
    int x = idx % MS; int t = idx / MS; int y = t % MS; int n = t / MS;
    const float* p = markers + n*3*4096;
    int py0 = min(max(y-4, 0), 255) >> 2;
    int py1 = min(max(y,   0), 255) >> 2;
    int px0 = min(max(x-4, 0), 255) >> 2;
    int px1 = min(max(x,   0), 255) >> 2;
    float B00=0.f, B01=0.f, B10=0.f, B11=0.f;
    #pragma unroll
    for (int ky = 0; ky < 5; ++ky) {
      int py = min(max(y + ky - 4, 0), 255) >> 2;
      bool r1 = (py == py1) && (py1 != py0);
      #pragma unroll
      for (int kx = 0; kx < 5; ++kx) {
        int px = min(max(x + kx - 4, 0), 255) >> 2;
        bool c1 = (px == px1) && (px1 != px0);
        float w = K.v[ky*5+kx];
        if (r1) { if (c1) B11 += w; else B10 += w; }
        else    { if (c1) B01 += w; else B00 += w; }
      }
    }
    int o00 = py0*64+px0, o01 = py0*64+px1, o10 = py1*64+px0, o11 = py1*64+px1;
    float a0 = B00*p[o00]      + B01*p[o01]      + B10*p[o10]      + B11*p[o11];
    float a1 = B00*p[4096+o00] + B01*p[4096+o01] + B10*p[4096+o10] + B11*p[4096+o11];
    float a2 = B00*p[8192+o00] + B01*p[8192+o01] + B10*p[8192+o10] + B11*p[8192+o11];
    int o = idx*3;
    fp[o+0]=a0; fp[o+1]=a1; fp[o+2]=a2;
    return;
  }

  if (b < 1 + BLUR_B + FAM_B) {
    int idx = (b-1-BLUR_B)*256 + tid;
    if (idx >= FAM_N) return;
    int x = idx % MS, y = idx / MS;
    float a = 0.f;
    #pragma unroll
    for (int ky = 0; ky < 5; ++ky) {
      int iy = y + ky;
      bool oy = (iy >= 4) && (iy < MS);
      #pragma unroll
      for (int kx = 0; kx < 5; ++kx) {
        int ix = x + kx;
        bool ox = (ix >= 4) && (ix < MS);
        if (oy && ox) a += K.v[ky*5+kx];
      }
    }
    faM[idx] = a;
    return;
  }

  {
    int idx = (b-1-BLUR_B-FAM_B)*256 + tid;
    if (idx >= FAB_N) return;
    int x = idx % BS, y = idx / BS;
    float a = 0.f;
    #pragma unroll
    for (int ky = 0; ky < 5; ++ky) {
      int iy = y + ky;
      bool oy = (iy >= 4) && (iy < BS);
      #pragma unroll
      for (int kx = 0; kx < 5; ++kx) {
        int ix = x + kx;
        bool ox = (ix >= 4) && (ix < BS);
        if (oy && ox) a += K.v[ky*5+kx];
      }
    }
    faB[idx] = a;
    return;
  }
}

// ---------------------------------------------------------------------------
// Main fused per-pixel kernel — 2 pixels per thread, float2 I/O.
// (4->2 px/thread: halves live accumulator VGPRs and doubles wave count for
//  better gather-latency hiding in board regions; traffic unchanged.)
// Board-bbox early-out: outside all board bboxes, out == image exactly.
// ---------------------------------------------------------------------------
__global__ __launch_bounds__(256) void main_kernel(
    const float* __restrict__ image, const float* __restrict__ vd,
    const float* __restrict__ noise, const float* __restrict__ diffuse,
    const float* __restrict__ refl, const float* __restrict__ bn,
    const float* __restrict__ rough, const float* __restrict__ minv,
    const int* __restrict__ bbox, const float* __restrict__ spow,
    const float* __restrict__ fp, const float* __restrict__ faM,
    const float* __restrict__ faB, float* __restrict__ out) {
  __shared__ float s_minv[108];
  __shared__ int   s_bbox[48];
  __shared__ float s_spow[12], s_refl[12], s_bn[12], s_diff[12], s_rough[4];
  int tid = threadIdx.x;
  if (tid < 108) s_minv[tid] = minv[tid];
  if (tid < 48)  s_bbox[tid] = bbox[tid];
  if (tid < 12) {
    s_spow[tid] = spow[tid]; s_refl[tid] = refl[tid];
    s_bn[tid]   = bn[tid];   s_diff[tid] = diffuse[tid];
  }
  if (tid < 4) s_rough[tid] = rough[tid];
  __syncthreads();

  int base = (blockIdx.x*256 + tid)*2;   // WW%2==0 -> never wraps a row
  int x0i = base % WW;
  int y   = base / WW;

  // ---- board-bbox early-out ----
  bool hasBoard = false;
  #pragma unroll
  for (int n = 0; n < NBRD; ++n) {
    const int* bb = &s_bbox[(NM+n)*4];
    hasBoard |= (y >= bb[1]) && (y < bb[3]) && (x0i+1 >= bb[0]) && (x0i < bb[2]);
  }
  if (!hasBoard) {
    *(float2*)(out + base)          = *(const float2*)(image + base);
    *(float2*)(out + NPIX + base)   = *(const float2*)(image + NPIX + base);
    *(float2*)(out + 2*NPIX + base) = *(const float2*)(image + 2*NPIX + base);
    return;
  }

  float pyc = (float)y + 0.5f;

  // ---- markers ----
  float pm0[2]={0,0}, pm1[2]={0,0}, pm2[2]={0,0}, pma[2]={0,0};
  for (int n = 0; n < NM; ++n) {
    const int* bb = &s_bbox[n*4];
    if (y < bb[1] || y >= bb[3] || x0i+1 < bb[0] || x0i >= bb[2]) continue;
    const float* m = &s_minv[n*9];
    #pragma unroll
    for (int k = 0; k < 2; ++k) {
      int x = x0i + k;
      if (x < bb[0] || x >= bb[2]) continue;
      float pxc = (float)x + 0.5f;
      float X = m[0]*pxc + m[1]*pyc + m[2];
      float Y = m[3]*pxc + m[4]*pyc + m[5];
      float Z = m[6]*pxc + m[7]*pyc + m[8];
      float sc = (fabsf(Z) > 1e-8f) ? 1.0f/(Z + 1e-8f) : 1.0f;
      float gx = (X*sc + 1.0f)*(0.5f*MS) - 0.5f;
      float gy = (Y*sc + 1.0f)*(0.5f*MS) - 0.5f;
      float x0f = floorf(gx), y0f = floorf(gy);
      float wx = gx - x0f, wy = gy - y0f;
      int ix0 = (int)x0f, iy0 = (int)y0f, ix1 = ix0+1, iy1 = iy0+1;
      bool okx0 = (ix0 >= 0) & (ix0 < MS), okx1 = (ix1 >= 0) & (ix1 < MS);
      bool oky0 = (iy0 >= 0) & (iy0 < MS), oky1 = (iy1 >= 0) & (iy1 < MS);
      int cx0 = min(max(ix0,0),MS-1), cx1 = min(max(ix1,0),MS-1);
      int cy0 = min(max(iy0,0),MS-1), cy1 = min(max(iy1,0),MS-1);
      float w00 = (okx0&&oky0) ? (1.f-wx)*(1.f-wy) : 0.f;
      float w10 = (okx1&&oky0) ? wx*(1.f-wy)       : 0.f;
      float w01 = (okx0&&oky1) ? (1.f-wx)*wy       : 0.f;
      float w11 = (okx1&&oky1) ? wx*wy             : 0.f;
      int i00 = cy0*MS+cx0, i10 = cy0*MS+cx1, i01 = cy1*MS+cx0, i11 = cy1*MS+cx1;
      const float* f0 = fp + (size_t)n*MS*MS*3;
      const float* t00 = f0 + i00*3; const float* t10 = f0 + i10*3;
      const float* t01 = f0 + i01*3; const float* t11 = f0 + i11*3;
      pm0[k] += t00[0]*w00 + t10[0]*w10 + t01[0]*w01 + t11[0]*w11;
      pm1[k] += t00[1]*w00 + t10[1]*w10 + t01[1]*w01 + t11[1]*w11;
      pm2[k] += t00[2]*w00 + t10[2]*w10 + t01[2]*w01 + t11[2]*w11;
      pma[k] += faM[i00]*w00 + faM[i10]*w10 + faM[i01]*w01 + faM[i11]*w11;
    }
  }

  // ---- boards ----
  float pb0[2]={0,0}, pb1[2]={0,0}, pb2[2]={0,0}, pba[2]={0,0};
  float sd0[2]={0,0}, sd1[2]={0,0}, sd2[2]={0,0};
  float sn0[2]={0,0}, sn1[2]={0,0}, sn2[2]={0,0};
  float rg[2]={0,0},  sp0[2]={0,0}, sp1[2]={0,0}, sp2[2]={0,0};
  for (int n = 0; n < NBRD; ++n) {
    int bix = NM + n;
    const int* bb = &s_bbox[bix*4];
    if (y < bb[1] || y >= bb[3] || x0i+1 < bb[0] || x0i >= bb[2]) continue;
    const float* m = &s_minv[bix*9];
    #pragma unroll
    for (int k = 0; k < 2; ++k) {
      int x = x0i + k;
      if (x < bb[0] || x >= bb[2]) continue;
      float pxc = (float)x + 0.5f;
      float X = m[0]*pxc + m[1]*pyc + m[2];
      float Y = m[3]*pxc + m[4]*pyc + m[5];
      float Z = m[6]*pxc + m[7]*pyc + m[8];
      float sc = (fabsf(Z) > 1e-8f) ? 1.0f/(Z + 1e-8f) : 1.0f;
      float gx = (X*sc + 1.0f)*(0.5f*BS) - 0.5f;
      float gy = (Y*sc + 1.0f)*(0.5f*BS) - 0.5f;
      float x0f = floorf(gx), y0f = floorf(gy);
      float wx = gx - x0f, wy = gy - y0f;
      int ix0 = (int)x0f, iy0 = (int)y0f, ix1 = ix0+1, iy1 = iy0+1;
      bool okx0 = (ix0 >= 0) & (ix0 < BS), okx1 = (ix1 >= 0) & (ix1 < BS);
      bool oky0 = (iy0 >= 0) & (iy0 < BS), oky1 = (iy1 >= 0) & (iy1 < BS);
      int cx0 = min(max(ix0,0),BS-1), cx1 = min(max(ix1,0),BS-1);
      int cy0 = min(max(iy0,0),BS-1), cy1 = min(max(iy1,0),BS-1);
      float w00 = (okx0&&oky0) ? (1.f-wx)*(1.f-wy) : 0.f;
      float w10 = (okx1&&oky0) ? wx*(1.f-wy)       : 0.f;
      float w01 = (okx0&&oky1) ? (1.f-wx)*wy       : 0.f;
      float w11 = (okx1&&oky1) ? wx*wy             : 0.f;
      int i00 = cy0*BS+cx0, i10 = cy0*BS+cx1, i01 = cy1*BS+cx0, i11 = cy1*BS+cx1;
      float cov = w00 + w10 + w01 + w11;
      float pa  = faB[i00]*w00 + faB[i10]*w10 + faB[i01]*w01 + faB[i11]*w11;
      pb0[k] += s_diff[n*3+0]*cov;
      pb1[k] += s_diff[n*3+1]*cov;
      pb2[k] += s_diff[n*3+2]*cov;
      pba[k] += pa;
      float hd = (pa != 0.f) ? 1.f : 0.f;
      sd0[k] += hd*s_refl[n*3+0]; sd1[k] += hd*s_refl[n*3+1]; sd2[k] += hd*s_refl[n*3+2];
      sn0[k] += hd*s_bn[n*3+0];   sn1[k] += hd*s_bn[n*3+1];   sn2[k] += hd*s_bn[n*3+2];
      rg[k]  += hd*s_rough[n];
      sp0[k] += pa*s_spow[n*3+0]; sp1[k] += pa*s_spow[n*3+1]; sp2[k] += pa*s_spow[n*3+2];
    }
  }

  // ---- vectorized loads ----
  float i0a[2], i1a[2], i2a[2], n0a[2], n1a[2], n2a[2], vdl[6];
  *(float2*)i0a = *(const float2*)(image + base);
  *(float2*)i1a = *(const float2*)(image + NPIX + base);
  *(float2*)i2a = *(const float2*)(image + 2*NPIX + base);
  *(float2*)n0a = *(const float2*)(noise + base);
  *(float2*)n1a = *(const float2*)(noise + NPIX + base);
  *(float2*)n2a = *(const float2*)(noise + 2*NPIX + base);
  *(float2*)&vdl[0] = *(const float2*)(vd + (size_t)base*3);
  *(float2*)&vdl[2] = *(const float2*)(vd + (size_t)base*3 + 2);
  *(float2*)&vdl[4] = *(const float2*)(vd + (size_t)base*3 + 4);

  float o0a[2], o1a[2], o2a[2];
  #pragma unroll
  for (int k = 0; k < 2; ++k) {
    float st0 = pb0[k]*(1.f-pma[k]) + pb0[k]*pm0[k]*pma[k];
    float st1 = pb1[k]*(1.f-pma[k]) + pb1[k]*pm1[k]*pma[k];
    float st2 = pb2[k]*(1.f-pma[k]) + pb2[k]*pm2[k]*pma[k];
    float fin0 = i0a[k]*(1.f-pba[k]) + i0a[k]*pba[k]*st0;
    float fin1 = i1a[k]*(1.f-pba[k]) + i1a[k]*pba[k]*st1;
    float fin2 = i2a[k]*(1.f-pba[k]) + i2a[k]*pba[k]*st2;

    float nx = sn0[k] + n0a[k];
    float ny = sn1[k] + n1a[k];
    float nz = sn2[k] + n2a[k];
    float nl = fmaxf(sqrtf(nx*nx+ny*ny+nz*nz), 1e-8f);
    nx /= nl; ny /= nl; nz /= nl;
    float vx = vdl[3*k+0], vy = vdl[3*k+1], vz = vdl[3*k+2];
    float hx = (sd0[k]+vx)*0.5f, hy = (sd1[k]+vy)*0.5f, hz = (sd2[k]+vz)*0.5f;
    float hl = fmaxf(sqrtf(hx*hx+hy*hy+hz*hz), 1e-8f);
    hx /= hl; hy /= hl; hz /= hl;
    float NoH = fmaxf(0.f, nx*hx+ny*hy+nz*hz);
    float NoV = fmaxf(0.f, nx*vx+ny*vy+nz*vz);
    float NoL = fmaxf(0.f, nx*sd0[k]+ny*sd1[k]+nz*sd2[k]);
    float VoH = fmaxf(0.f, vx*hx+vy*hy+vz*hz);
    float al = rg[k]*rg[k];
    float tmp = al / fmaxf(NoH*NoH*(al*al-1.f)+1.f, 1e-8f);
    float D = tmp*tmp*(float)(1.0/M_PI);
    float kk = al*0.5f;
    float G = NoL*NoV / fmaxf((NoL*(1.f-kk)+kk)*(NoV*(1.f-kk)+kk), 1e-8f);
    float co = VoH*(-5.55473f*VoH - 6.98316f);
    float F = 0.1f + 0.9f*exp2f(co);
    float f_s = D*G*F / fmaxf(4.f*NoL*NoV, 1e-8f);
    float spec = f_s*NoL*(float)M_PI;

    o0a[k] = fin0 + spec*sp0[k];
    o1a[k] = fin1 + spec*sp1[k];
    o2a[k] = fin2 + spec*sp2[k];
  }
  *(float2*)(out + base)          = *(float2*)o0a;
  *(float2*)(out + NPIX + base)   = *(float2*)o1a;
  *(float2*)(out + 2*NPIX + base) = *(float2*)o2a;
}

// ---------------------------------------------------------------------------
extern "C" void kernel_launch(void* const* d_in, const int* in_sizes, int n_in,
                              void* d_out, int out_size, void* d_ws, size_t ws_size,
                              hipStream_t stream) {
  const float* image    = (const float*)d_in[0];
  const float* vdirs    = (const float*)d_in[1];
  const float* markers  = (const float*)d_in[2];
  const float* marker_h = (const float*)d_in[3];
  const float* board_h  = (const float*)d_in[4];
  const float* refl     = (const float*)d_in[5];
  const float* bview    = (const float*)d_in[6];
  const float* bnorm    = (const float*)d_in[7];
  const float* avg_col  = (const float*)d_in[8];
  const float* bmax     = (const float*)d_in[9];
  const float* rough    = (const float*)d_in[10];
  const float* diffuse  = (const float*)d_in[11];
  const float* sscale   = (const float*)d_in[12];
  const float* noise    = (const float*)d_in[13];

  float* ws   = (float*)d_ws;
  float* minv = ws + OFF_MINV;
  int*   bbox = (int*)(ws + OFF_BBOX);
  float* spow = ws + OFF_SPOW;
  float* faM  = ws + OFF_FAM;
  float* faB  = ws + OFF_FAB;
  float* fp   = ws + OFF_FP;
  float* outp = (float*)d_out;

  // disk kernel on host in f64 (bit-matches numpy) -> pass by value
  K25 K;
  {
    double w[25]; double s = 0.0;
    for (int dy = -2; dy <= 2; ++dy)
      for (int dx = -2; dx <= 2; ++dx) {
        double d = sqrt((double)(dx*dx + dy*dy));
        double v = 2.5 - d;
        v = v < 0.0 ? 0.0 : (v > 1.0 ? 1.0 : v);
        w[(dy+2)*5 + (dx+2)] = v; s += v;
      }
    for (int i = 0; i < 25; ++i) K.v[i] = (float)(w[i]/s);
  }

  hipLaunchKernelGGL(precompute_kernel, dim3(PRE_B), dim3(256), 0, stream,
                     markers, marker_h, board_h, refl, bview, bnorm, avg_col,
                     bmax, rough, sscale, minv, bbox, spow, fp, faM, faB, K);
  hipLaunchKernelGGL(main_kernel, dim3(NPIX/512), dim3(256), 0, stream,
                     image, vdirs, noise, diffuse, refl, bnorm, rough,
                     minv, bbox, spow, fp, faM, faB, outp);
}